// Round 1
// baseline (516.074 us; speedup 1.0000x reference)
//
#include <hip/hip_runtime.h>
#include <stdint.h>

typedef unsigned short u16;
typedef __bf16 bf16x8 __attribute__((ext_vector_type(8)));
typedef float f32x4 __attribute__((ext_vector_type(4)));
typedef __attribute__((address_space(3))) void as3_void;
typedef __attribute__((address_space(1))) void as1_void;

#define NU   1024
#define NB   8192
#define LDW  2048

// Newton-Schulz degree-1 minimax init for 1/lambda on [2, 13.8]:
// X0 = NS_A*I + NS_B*M  ->  ||I - M X0|| <= 0.387
#define NS_A 0.351071f
#define NS_B (-0.0222197f)

// ---------- bf16 helpers (RNE, bit ops; inputs finite) ----------
__device__ __forceinline__ u16 f2h(float f) {
  union { float f; uint32_t u; } c; c.f = f;
  uint32_t r = (c.u + 0x7fffu + ((c.u >> 16) & 1u)) >> 16;
  return (u16)r;
}
__device__ __forceinline__ float h2f(u16 h) {
  union { uint32_t u; float f; } c; c.u = ((uint32_t)h) << 16;
  return c.f;
}

__device__ __forceinline__ void gload16(const u16* g, u16* l) {
  __builtin_amdgcn_global_load_lds((const as1_void*)g, (as3_void*)l, 16, 0, 0);
}

// ---------- prep: B0 -> bf16 hi/lo, plain and transposed ----------
__global__ void prep_b0(const float* __restrict__ B0, u16* __restrict__ B0h,
                        u16* __restrict__ B0l, u16* __restrict__ B0Th,
                        u16* __restrict__ B0Tl) {
  __shared__ float t[32][33];
  const int bx = blockIdx.x, by = blockIdx.y;
  const int x = threadIdx.x, y0 = threadIdx.y;
  #pragma unroll
  for (int yy = y0; yy < 32; yy += 8) {
    const int r = by * 32 + yy, c = bx * 32 + x;
    const float v = B0[(size_t)r * NU + c];
    t[yy][x] = v;
    const u16 hh = f2h(v);
    B0h[(size_t)r * NU + c] = hh;
    B0l[(size_t)r * NU + c] = f2h(v - h2f(hh));
  }
  __syncthreads();
  #pragma unroll
  for (int yy = y0; yy < 32; yy += 8) {
    const int r = bx * 32 + yy, c = by * 32 + x;  // B0T[r][c] = B0[c][r]
    const float v = t[x][yy];
    const u16 hh = f2h(v);
    B0Th[(size_t)r * NU + c] = hh;
    B0Tl[(size_t)r * NU + c] = f2h(v - h2f(hh));
  }
}

// ---------- zzT[b][i] = z1, zzT[b][i+NU] = z2 (transposed, bf16) ----------
__global__ void build_zzT(const float* __restrict__ v0, const float* __restrict__ v1,
                          const float* __restrict__ q, u16* __restrict__ zzT) {
  __shared__ u16 z1t[32][33], z2t[32][33];
  const int bx = blockIdx.x;  // batch tile
  const int by = blockIdx.y;  // unit tile
  const int x = threadIdx.x, y0 = threadIdx.y;
  #pragma unroll
  for (int yy = y0; yy < 32; yy += 8) {
    const int i = by * 32 + yy;
    const int b = bx * 32 + x;
    const float a0 = v0[(size_t)i * NB + b];
    const float a1 = v1[(size_t)i * NB + b];
    z1t[yy][x] = f2h(a0 + 0.1f * q[i]);          // z1 = v0 + DT*q
    z2t[yy][x] = f2h(a1 + tanhf(a0));            // z2 = v1 + (DT/EPS)*tanh(v0)
  }
  __syncthreads();
  #pragma unroll
  for (int yy = y0; yy < 32; yy += 8) {
    const int b = bx * 32 + yy;
    const int i = by * 32 + x;
    zzT[(size_t)b * LDW + i]      = z1t[x][yy];
    zzT[(size_t)b * LDW + NU + i] = z2t[x][yy];
  }
}

// ---------- bf16 1024x1024 transpose, optional negate (sign-bit flip) ----------
__global__ void transpose_h(const u16* __restrict__ in, int ldi,
                            u16* __restrict__ out, int ldo, int flip) {
  __shared__ u16 t[32][33];
  const int bx = blockIdx.x, by = blockIdx.y;
  const int x = threadIdx.x, y0 = threadIdx.y;
  #pragma unroll
  for (int yy = y0; yy < 32; yy += 8)
    t[yy][x] = in[(size_t)(by * 32 + yy) * ldi + bx * 32 + x];
  __syncthreads();
  const u16 m = flip ? (u16)0x8000u : (u16)0;
  #pragma unroll
  for (int yy = y0; yy < 32; yy += 8)
    out[(size_t)(bx * 32 + yy) * ldo + by * 32 + x] = (u16)(t[x][yy] ^ m);
}

// ---------- X0 = NS_A*I + NS_B*M ----------
__global__ void init_x0(const u16* __restrict__ Mh, u16* __restrict__ X) {
  const int idx = blockIdx.x * 256 + threadIdx.x;
  const int i = idx >> 10, j = idx & 1023;
  const float v = NS_B * h2f(Mh[idx]) + ((i == j) ? NS_A : 0.f);
  X[idx] = f2h(v);
}

// ---------- NT-form bf16 GEMM: C = A * Bt^T ----------
// Both operands stored [rows][K] row-major (K contiguous).
// Products accumulated: A0*Bt0^T (+ A1*Bt0^T if A1) (+ A0*Bt1^T if Bt1).
// Epilogue: v = alpha*acc + beta*AUX[gr][gc] + gamma*(gr==gc);
// outputs: fp32 (outF) and/or bf16 (outH) with optional lo part (outL).
__global__ __launch_bounds__(256)
void gemm_nt(const u16* __restrict__ A0, const u16* __restrict__ A1, int lda,
             const u16* __restrict__ Bt0, const u16* __restrict__ Bt1, int ldb,
             const u16* __restrict__ AUX, int ldaux,
             float alpha, float beta, float gamma,
             float* __restrict__ outF, u16* __restrict__ outH, u16* __restrict__ outL,
             int ldc, int M, int N, int K) {
  __shared__ u16 lds[4][128 * 32];  // A0 | Bt0 | A1 | Bt1 tiles, 8 KB each

  const int nTn = N >> 7;
  const int nwg = (int)gridDim.x;
  int wg = (int)blockIdx.x;
  if ((nwg & 7) == 0) {  // bijective XCD swizzle (nwg % 8 == 0 in all our launches)
    const int c = nwg >> 3;
    wg = (wg & 7) * c + (wg >> 3);
  }
  const int tm = wg / nTn, tn = wg % nTn;
  const int row0 = tm << 7, col0 = tn << 7;

  const int tid = threadIdx.x;
  const int lane = tid & 63;
  const int wid = tid >> 6;
  const int wm = wid >> 1, wn = wid & 1;   // 2x2 waves, 64x64 each
  const int r16 = lane & 15, ch = lane >> 4;

  const bool hasA1 = (A1 != nullptr);
  const bool hasB1 = (Bt1 != nullptr);

  f32x4 acc[4][4] = {};

  const int nK = K >> 5;
  for (int kt = 0; kt < nK; ++kt) {
    const int k0 = kt << 5;
    #pragma unroll
    for (int h = 0; h < 2; ++h) {
      const int L = tid + (h << 8);
      const int row = L >> 2, seg = L & 3;
      const int ss = seg ^ (row & 3);  // XOR swizzle: source seg for linear dest
      const size_t goffA = (size_t)(row0 + row) * lda + (size_t)(k0 + (ss << 3));
      const size_t goffB = (size_t)(col0 + row) * ldb + (size_t)(k0 + (ss << 3));
      u16* dst = nullptr;
      const int dofs = (L & ~63) << 3;  // wave-uniform LDS base (elements)
      gload16(A0 + goffA, &lds[0][dofs]);
      gload16(Bt0 + goffB, &lds[1][dofs]);
      if (hasA1) gload16(A1 + goffA, &lds[2][dofs]);
      if (hasB1) gload16(Bt1 + goffB, &lds[3][dofs]);
      (void)dst;
    }
    __syncthreads();

    bf16x8 av[4], bv[4];
    #pragma unroll
    for (int f = 0; f < 4; ++f) {
      const int ra = (wm << 6) + (f << 4) + r16;
      av[f] = *(const bf16x8*)&lds[0][(ra << 5) + (((ch ^ ra) & 3) << 3)];
      const int rb = (wn << 6) + (f << 4) + r16;
      bv[f] = *(const bf16x8*)&lds[1][(rb << 5) + (((ch ^ rb) & 3) << 3)];
    }
    #pragma unroll
    for (int fm = 0; fm < 4; ++fm)
      #pragma unroll
      for (int fn = 0; fn < 4; ++fn)
        acc[fm][fn] = __builtin_amdgcn_mfma_f32_16x16x32_bf16(av[fm], bv[fn], acc[fm][fn], 0, 0, 0);

    if (hasA1) {
      bf16x8 a1[4];
      #pragma unroll
      for (int f = 0; f < 4; ++f) {
        const int ra = (wm << 6) + (f << 4) + r16;
        a1[f] = *(const bf16x8*)&lds[2][(ra << 5) + (((ch ^ ra) & 3) << 3)];
      }
      #pragma unroll
      for (int fm = 0; fm < 4; ++fm)
        #pragma unroll
        for (int fn = 0; fn < 4; ++fn)
          acc[fm][fn] = __builtin_amdgcn_mfma_f32_16x16x32_bf16(a1[fm], bv[fn], acc[fm][fn], 0, 0, 0);
    }
    if (hasB1) {
      bf16x8 b1[4];
      #pragma unroll
      for (int f = 0; f < 4; ++f) {
        const int rb = (wn << 6) + (f << 4) + r16;
        b1[f] = *(const bf16x8*)&lds[3][(rb << 5) + (((ch ^ rb) & 3) << 3)];
      }
      #pragma unroll
      for (int fm = 0; fm < 4; ++fm)
        #pragma unroll
        for (int fn = 0; fn < 4; ++fn)
          acc[fm][fn] = __builtin_amdgcn_mfma_f32_16x16x32_bf16(av[fm], b1[fn], acc[fm][fn], 0, 0, 0);
    }
    __syncthreads();
  }

  // epilogue: C/D layout (m89-verified): col = lane&15, row = (lane>>4)*4 + j
  const int rbase = row0 + (wm << 6) + ((lane >> 4) << 2);
  const int cbase = col0 + (wn << 6) + (lane & 15);
  #pragma unroll
  for (int fm = 0; fm < 4; ++fm) {
    #pragma unroll
    for (int fn = 0; fn < 4; ++fn) {
      #pragma unroll
      for (int j = 0; j < 4; ++j) {
        const int gr = rbase + (fm << 4) + j;
        const int gc = cbase + (fn << 4);
        float v = alpha * acc[fm][fn][j];
        if (AUX) v += beta * h2f(AUX[(size_t)gr * ldaux + gc]);
        if (gamma != 0.f && gr == gc) v += gamma;
        const size_t off = (size_t)gr * ldc + gc;
        if (outF) outF[off] = v;
        if (outH) {
          const u16 hh = f2h(v);
          outH[off] = hh;
          if (outL) outL[off] = f2h(v - h2f(hh));
        }
      }
    }
  }
}

extern "C" void kernel_launch(void* const* d_in, const int* in_sizes, int n_in,
                              void* d_out, int out_size, void* d_ws, size_t ws_size,
                              hipStream_t stream) {
  (void)in_sizes; (void)n_in; (void)out_size; (void)ws_size;
  const float* v0 = (const float*)d_in[0];
  const float* v1 = (const float*)d_in[1];
  const float* B0 = (const float*)d_in[2];
  const float* q  = (const float*)d_in[3];
  float* out = (float*)d_out;

  size_t off = 0;
  char* base = (char*)d_ws;
  auto alloc = [&](size_t bytes) -> u16* {
    char* r = base + off;
    off += (bytes + 255) & ~(size_t)255;
    return (u16*)r;
  };
  u16* zzT  = alloc((size_t)NB * LDW * 2);   // 33.6 MB
  u16* W    = alloc((size_t)LDW * LDW * 2);  //  8.4 MB
  u16* B0h  = alloc((size_t)NU * NU * 2);
  u16* B0l  = alloc((size_t)NU * NU * 2);
  u16* B0Th = alloc((size_t)NU * NU * 2);
  u16* B0Tl = alloc((size_t)NU * NU * 2);
  u16* Mh   = alloc((size_t)NU * NU * 2);
  u16* Ml   = alloc((size_t)NU * NU * 2);
  u16* X0b  = alloc((size_t)NU * NU * 2);
  u16* X1b  = alloc((size_t)NU * NU * 2);
  u16* Tb   = alloc((size_t)NU * NU * 2);
  u16* Xt   = alloc((size_t)NU * NU * 2);    // total ~63 MB

  u16* W00 = W;
  u16* W01 = W + NU;
  u16* W10 = W + (size_t)NU * LDW;
  u16* W11 = W + (size_t)NU * LDW + NU;

  prep_b0<<<dim3(32, 32), dim3(32, 8), 0, stream>>>(B0, B0h, B0l, B0Th, B0Tl);
  build_zzT<<<dim3(NB / 32, NU / 32), dim3(32, 8), 0, stream>>>(v0, v1, q, zzT);

  // M = 2I + B0^T B0 in split precision (hh + lh + hl), emitted as Mh+Ml
  gemm_nt<<<64, 256, 0, stream>>>(B0Th, B0Tl, NU, B0Th, B0Tl, NU,
                                  nullptr, 0, 1.f, 0.f, 2.f,
                                  nullptr, Mh, Ml, NU, NU, NU, NU);
  init_x0<<<NU * NU / 256, 256, 0, stream>>>(Mh, X0b);

  // Newton-Schulz: X <- 2X - X*(M*X), 4 iterations in bf16
  u16* cur = X0b; u16* oth = X1b;
  for (int it = 0; it < 4; ++it) {
    gemm_nt<<<64, 256, 0, stream>>>(Mh, nullptr, NU, cur, nullptr, NU,
                                    nullptr, 0, 1.f, 0.f, 0.f,
                                    nullptr, Tb, nullptr, NU, NU, NU, NU);       // T = M X^T
    gemm_nt<<<64, 256, 0, stream>>>(cur, nullptr, NU, Tb, nullptr, NU,
                                    cur, NU, -1.f, 2.f, 0.f,
                                    nullptr, oth, nullptr, NU, NU, NU, NU);      // X' = 2X - X T^T
    u16* t = cur; cur = oth; oth = t;
  }

  // exact residual refinement: E = I - M*X (split M, exact via transpose), X <- X + X*E
  transpose_h<<<dim3(32, 32), dim3(32, 8), 0, stream>>>(cur, NU, Xt, NU, 0);     // X^T
  gemm_nt<<<64, 256, 0, stream>>>(Mh, Ml, NU, Xt, nullptr, NU,
                                  nullptr, 0, -1.f, 0.f, 1.f,
                                  nullptr, Tb, nullptr, NU, NU, NU, NU);         // E = I - M X
  transpose_h<<<dim3(32, 32), dim3(32, 8), 0, stream>>>(Tb, NU, oth, NU, 0);     // E^T
  gemm_nt<<<64, 256, 0, stream>>>(cur, nullptr, NU, oth, nullptr, NU,
                                  cur, NU, 1.f, 1.f, 0.f,
                                  nullptr, W11, nullptr, LDW, NU, NU, NU);       // P -> W11

  // Q = P B0^T -> W10 ;  W01 = -Q^T ;  S = I - B0 Q -> W00
  gemm_nt<<<64, 256, 0, stream>>>(W11, nullptr, LDW, B0h, nullptr, NU,
                                  nullptr, 0, 1.f, 0.f, 0.f,
                                  nullptr, W10, nullptr, LDW, NU, NU, NU);
  transpose_h<<<dim3(32, 32), dim3(32, 8), 0, stream>>>(W10, LDW, Tb, NU, 0);    // Q^T
  transpose_h<<<dim3(32, 32), dim3(32, 8), 0, stream>>>(W10, LDW, W01, LDW, 1);  // -Q^T
  gemm_nt<<<64, 256, 0, stream>>>(B0h, nullptr, NU, Tb, nullptr, NU,
                                  nullptr, 0, -1.f, 0.f, 1.f,
                                  nullptr, W00, nullptr, LDW, NU, NU, NU);

  // [x; y] = W * [z1; z2]  (2048 x 8192 x 2048), fp32 out straight into d_out
  gemm_nt<<<(LDW / 128) * (NB / 128), 256, 0, stream>>>(W, nullptr, LDW, zzT, nullptr, LDW,
                                  nullptr, 0, 1.f, 0.f, 0.f,
                                  out, nullptr, nullptr, NB, LDW, NB, LDW);
}

// Round 2
// 322.087 us; speedup vs baseline: 1.6023x; 1.6023x over previous
//
#include <hip/hip_runtime.h>
#include <stdint.h>

typedef unsigned short u16;
typedef __bf16 bf16x8 __attribute__((ext_vector_type(8)));
typedef float f32x4 __attribute__((ext_vector_type(4)));
typedef __attribute__((address_space(3))) void as3_void;
typedef __attribute__((address_space(1))) void as1_void;

#define NU   1024
#define NB   8192
#define LDW  2048

// Newton-Schulz degree-1 minimax init for 1/lambda on [2, 13.8]:
// X0 = NS_A*I + NS_B*M  ->  ||I - M X0|| <= 0.387
#define NS_A 0.351071f
#define NS_B (-0.0222197f)

// ---------- bf16 helpers (RNE, bit ops; inputs finite) ----------
__device__ __forceinline__ u16 f2h(float f) {
  union { float f; uint32_t u; } c; c.f = f;
  uint32_t r = (c.u + 0x7fffu + ((c.u >> 16) & 1u)) >> 16;
  return (u16)r;
}
__device__ __forceinline__ float h2f(u16 h) {
  union { uint32_t u; float f; } c; c.u = ((uint32_t)h) << 16;
  return c.f;
}

__device__ __forceinline__ void gload16(const u16* g, u16* l) {
  __builtin_amdgcn_global_load_lds((const as1_void*)g, (as3_void*)l, 16, 0, 0);
}

// ---------- prep: B0 -> bf16 hi/lo, plain and transposed ----------
__global__ void prep_b0(const float* __restrict__ B0, u16* __restrict__ B0h,
                        u16* __restrict__ B0l, u16* __restrict__ B0Th,
                        u16* __restrict__ B0Tl) {
  __shared__ float t[32][33];
  const int bx = blockIdx.x, by = blockIdx.y;
  const int x = threadIdx.x, y0 = threadIdx.y;
  #pragma unroll
  for (int yy = y0; yy < 32; yy += 8) {
    const int r = by * 32 + yy, c = bx * 32 + x;
    const float v = B0[(size_t)r * NU + c];
    t[yy][x] = v;
    const u16 hh = f2h(v);
    B0h[(size_t)r * NU + c] = hh;
    B0l[(size_t)r * NU + c] = f2h(v - h2f(hh));
  }
  __syncthreads();
  #pragma unroll
  for (int yy = y0; yy < 32; yy += 8) {
    const int r = bx * 32 + yy, c = by * 32 + x;  // B0T[r][c] = B0[c][r]
    const float v = t[x][yy];
    const u16 hh = f2h(v);
    B0Th[(size_t)r * NU + c] = hh;
    B0Tl[(size_t)r * NU + c] = f2h(v - h2f(hh));
  }
}

// ---------- zzT[b][i] = z1, zzT[b][i+NU] = z2 (transposed, bf16) ----------
__global__ void build_zzT(const float* __restrict__ v0, const float* __restrict__ v1,
                          const float* __restrict__ q, u16* __restrict__ zzT) {
  __shared__ u16 z1t[32][33], z2t[32][33];
  const int bx = blockIdx.x;  // batch tile
  const int by = blockIdx.y;  // unit tile
  const int x = threadIdx.x, y0 = threadIdx.y;
  #pragma unroll
  for (int yy = y0; yy < 32; yy += 8) {
    const int i = by * 32 + yy;
    const int b = bx * 32 + x;
    const float a0 = v0[(size_t)i * NB + b];
    const float a1 = v1[(size_t)i * NB + b];
    z1t[yy][x] = f2h(a0 + 0.1f * q[i]);          // z1 = v0 + DT*q
    z2t[yy][x] = f2h(a1 + tanhf(a0));            // z2 = v1 + (DT/EPS)*tanh(v0)
  }
  __syncthreads();
  #pragma unroll
  for (int yy = y0; yy < 32; yy += 8) {
    const int b = bx * 32 + yy;
    const int i = by * 32 + x;
    zzT[(size_t)b * LDW + i]      = z1t[x][yy];
    zzT[(size_t)b * LDW + NU + i] = z2t[x][yy];
  }
}

// ---------- bf16 transpose, optional negate (sign-bit flip) ----------
__global__ void transpose_h(const u16* __restrict__ in, int ldi,
                            u16* __restrict__ out, int ldo, int flip) {
  __shared__ u16 t[32][33];
  const int bx = blockIdx.x, by = blockIdx.y;
  const int x = threadIdx.x, y0 = threadIdx.y;
  #pragma unroll
  for (int yy = y0; yy < 32; yy += 8)
    t[yy][x] = in[(size_t)(by * 32 + yy) * ldi + bx * 32 + x];
  __syncthreads();
  const u16 m = flip ? (u16)0x8000u : (u16)0;
  #pragma unroll
  for (int yy = y0; yy < 32; yy += 8)
    out[(size_t)(bx * 32 + yy) * ldo + by * 32 + x] = (u16)(t[x][yy] ^ m);
}

// ---------- X0 = NS_A*I + NS_B*M ----------
__global__ void init_x0(const u16* __restrict__ Mh, u16* __restrict__ X) {
  const int idx = blockIdx.x * 256 + threadIdx.x;
  const int i = idx >> 10, j = idx & 1023;
  const float v = NS_B * h2f(Mh[idx]) + ((i == j) ? NS_A : 0.f);
  X[idx] = f2h(v);
}

// ---------- NT-form bf16 GEMM: C = A * Bt^T ----------
// Both operands stored [rows][K] row-major (K contiguous).
// Tile = BM x BN (BM = FM*32), 2x2 waves, BK=32.
// Products accumulated: A0*Bt0^T (+ A1*Bt0^T if A1) (+ A0*Bt1^T if Bt1) (NBUF=4).
// Epilogue: v = alpha*acc + beta*AUX[gr][gc] + gamma*(gr==gc);
// outputs: fp32 (outF) and/or bf16 (outH) with optional lo part (outL).
template<int FM, int FN, int NBUF>
__global__ __launch_bounds__(256)
void gemm_nt(const u16* __restrict__ A0, const u16* __restrict__ A1, int lda,
             const u16* __restrict__ Bt0, const u16* __restrict__ Bt1, int ldb,
             const u16* __restrict__ AUX, int ldaux,
             float alpha, float beta, float gamma,
             float* __restrict__ outF, u16* __restrict__ outH, u16* __restrict__ outL,
             int ldc, int M, int N, int K) {
  static_assert(FM == FN, "square tiles only");
  constexpr int BM = FM * 32;
  constexpr int R  = BM / 64;  // staging rounds per buffer (256 thr x 16B = 4KB)
  __shared__ u16 lds[NBUF][BM * 32];

  const int nTm = M / BM;
  const int nwg = (int)gridDim.x;
  int wg = (int)blockIdx.x;
  if ((nwg & 7) == 0) {  // bijective XCD swizzle (nwg % 8 == 0 in all our launches)
    const int c = nwg >> 3;
    wg = (wg & 7) * c + (wg >> 3);
  }
  // tn-major: each XCD owns a contiguous tn-slice (B-panel L2 locality)
  const int tm = wg % nTm, tn = wg / nTm;
  const int row0 = tm * BM, col0 = tn * BM;

  const int tid = threadIdx.x;
  const int lane = tid & 63;
  const int wid = tid >> 6;
  const int wm = wid >> 1, wn = wid & 1;   // 2x2 waves
  const int r16 = lane & 15, ch = lane >> 4;

  const bool hasA1 = (A1 != nullptr);
  const bool hasB1 = (Bt1 != nullptr);

  f32x4 acc[FM][FN] = {};

  const int nK = K >> 5;
  for (int kt = 0; kt < nK; ++kt) {
    const int k0 = kt << 5;
    #pragma unroll
    for (int h = 0; h < R; ++h) {
      const int L = tid + (h << 8);
      const int row = L >> 2, seg = L & 3;
      const int ss = seg ^ ((row >> 1) & 3);  // XOR swizzle (2-way = free)
      const size_t goffA = (size_t)(row0 + row) * lda + (size_t)(k0 + (ss << 3));
      const size_t goffB = (size_t)(col0 + row) * ldb + (size_t)(k0 + (ss << 3));
      const int dofs = (L & ~63) << 3;  // wave-uniform LDS base (elements)
      gload16(A0 + goffA, &lds[0][dofs]);
      gload16(Bt0 + goffB, &lds[1][dofs]);
      if constexpr (NBUF > 2) {
        if (hasA1) gload16(A1 + goffA, &lds[2][dofs]);
        if (hasB1) gload16(Bt1 + goffB, &lds[3][dofs]);
      }
    }
    __syncthreads();

    bf16x8 av[FM], bv[FN];
    #pragma unroll
    for (int f = 0; f < FM; ++f) {
      const int ra = wm * (FM * 16) + (f << 4) + r16;
      av[f] = *(const bf16x8*)&lds[0][(ra << 5) + ((((ch ^ (ra >> 1))) & 3) << 3)];
      const int rb = wn * (FN * 16) + (f << 4) + r16;
      bv[f] = *(const bf16x8*)&lds[1][(rb << 5) + ((((ch ^ (rb >> 1))) & 3) << 3)];
    }
    #pragma unroll
    for (int fm = 0; fm < FM; ++fm)
      #pragma unroll
      for (int fn = 0; fn < FN; ++fn)
        acc[fm][fn] = __builtin_amdgcn_mfma_f32_16x16x32_bf16(av[fm], bv[fn], acc[fm][fn], 0, 0, 0);

    if constexpr (NBUF > 2) {
      if (hasA1) {
        bf16x8 a1[FM];
        #pragma unroll
        for (int f = 0; f < FM; ++f) {
          const int ra = wm * (FM * 16) + (f << 4) + r16;
          a1[f] = *(const bf16x8*)&lds[2][(ra << 5) + ((((ch ^ (ra >> 1))) & 3) << 3)];
        }
        #pragma unroll
        for (int fm = 0; fm < FM; ++fm)
          #pragma unroll
          for (int fn = 0; fn < FN; ++fn)
            acc[fm][fn] = __builtin_amdgcn_mfma_f32_16x16x32_bf16(a1[fm], bv[fn], acc[fm][fn], 0, 0, 0);
      }
      if (hasB1) {
        bf16x8 b1[FN];
        #pragma unroll
        for (int f = 0; f < FN; ++f) {
          const int rb = wn * (FN * 16) + (f << 4) + r16;
          b1[f] = *(const bf16x8*)&lds[3][(rb << 5) + ((((ch ^ (rb >> 1))) & 3) << 3)];
        }
        #pragma unroll
        for (int fm = 0; fm < FM; ++fm)
          #pragma unroll
          for (int fn = 0; fn < FN; ++fn)
            acc[fm][fn] = __builtin_amdgcn_mfma_f32_16x16x32_bf16(av[fm], b1[fn], acc[fm][fn], 0, 0, 0);
      }
    }
    __syncthreads();
  }

  // epilogue: C/D layout (m89-verified): col = lane&15, row = (lane>>4)*4 + j
  const int rbase = row0 + wm * (FM * 16) + ((lane >> 4) << 2);
  const int cbase = col0 + wn * (FN * 16) + (lane & 15);
  #pragma unroll
  for (int fm = 0; fm < FM; ++fm) {
    #pragma unroll
    for (int fn = 0; fn < FN; ++fn) {
      #pragma unroll
      for (int j = 0; j < 4; ++j) {
        const int gr = rbase + (fm << 4) + j;
        const int gc = cbase + (fn << 4);
        float v = alpha * acc[fm][fn][j];
        if (AUX) v += beta * h2f(AUX[(size_t)gr * ldaux + gc]);
        if (gamma != 0.f && gr == gc) v += gamma;
        const size_t off = (size_t)gr * ldc + gc;
        if (outF) outF[off] = v;
        if (outH) {
          const u16 hh = f2h(v);
          outH[off] = hh;
          if (outL) outL[off] = f2h(v - h2f(hh));
        }
      }
    }
  }
}

extern "C" void kernel_launch(void* const* d_in, const int* in_sizes, int n_in,
                              void* d_out, int out_size, void* d_ws, size_t ws_size,
                              hipStream_t stream) {
  (void)in_sizes; (void)n_in; (void)out_size; (void)ws_size;
  const float* v0 = (const float*)d_in[0];
  const float* v1 = (const float*)d_in[1];
  const float* B0 = (const float*)d_in[2];
  const float* q  = (const float*)d_in[3];
  float* out = (float*)d_out;

  size_t off = 0;
  char* base = (char*)d_ws;
  auto alloc = [&](size_t bytes) -> u16* {
    char* r = base + off;
    off += (bytes + 255) & ~(size_t)255;
    return (u16*)r;
  };
  u16* zzT  = alloc((size_t)NB * LDW * 2);   // 33.6 MB
  u16* W    = alloc((size_t)LDW * LDW * 2);  //  8.4 MB
  u16* B0h  = alloc((size_t)NU * NU * 2);
  u16* B0l  = alloc((size_t)NU * NU * 2);
  u16* B0Th = alloc((size_t)NU * NU * 2);
  u16* B0Tl = alloc((size_t)NU * NU * 2);
  u16* Mh   = alloc((size_t)NU * NU * 2);
  u16* Ml   = alloc((size_t)NU * NU * 2);
  u16* X0b  = alloc((size_t)NU * NU * 2);
  u16* X1b  = alloc((size_t)NU * NU * 2);
  u16* Tb   = alloc((size_t)NU * NU * 2);
  u16* Xt   = alloc((size_t)NU * NU * 2);    // total ~63 MB

  u16* W00 = W;
  u16* W01 = W + NU;
  u16* W10 = W + (size_t)NU * LDW;
  u16* W11 = W + (size_t)NU * LDW + NU;

  prep_b0<<<dim3(32, 32), dim3(32, 8), 0, stream>>>(B0, B0h, B0l, B0Th, B0Tl);
  build_zzT<<<dim3(NB / 32, NU / 32), dim3(32, 8), 0, stream>>>(v0, v1, q, zzT);

  // M = 2I + B0^T B0 in split precision (hh + lh + hl), emitted as Mh+Ml
  gemm_nt<2,2,4><<<256, 256, 0, stream>>>(B0Th, B0Tl, NU, B0Th, B0Tl, NU,
                                  nullptr, 0, 1.f, 0.f, 2.f,
                                  nullptr, Mh, Ml, NU, NU, NU, NU);
  init_x0<<<NU * NU / 256, 256, 0, stream>>>(Mh, X0b);

  // Newton-Schulz: X <- 2X - X*(M*X), 3 iterations in bf16
  u16* cur = X0b; u16* oth = X1b;
  for (int it = 0; it < 3; ++it) {
    gemm_nt<2,2,2><<<256, 256, 0, stream>>>(Mh, nullptr, NU, cur, nullptr, NU,
                                    nullptr, 0, 1.f, 0.f, 0.f,
                                    nullptr, Tb, nullptr, NU, NU, NU, NU);       // T = M X^T
    gemm_nt<2,2,2><<<256, 256, 0, stream>>>(cur, nullptr, NU, Tb, nullptr, NU,
                                    cur, NU, -1.f, 2.f, 0.f,
                                    nullptr, oth, nullptr, NU, NU, NU, NU);      // X' = 2X - X T^T
    u16* t = cur; cur = oth; oth = t;
  }

  // exact residual refinement: E = I - M*X (split M), X <- X + X*E
  transpose_h<<<dim3(32, 32), dim3(32, 8), 0, stream>>>(cur, NU, Xt, NU, 0);     // X^T
  gemm_nt<2,2,4><<<256, 256, 0, stream>>>(Mh, Ml, NU, Xt, nullptr, NU,
                                  nullptr, 0, -1.f, 0.f, 1.f,
                                  nullptr, Tb, nullptr, NU, NU, NU, NU);         // E = I - M X
  transpose_h<<<dim3(32, 32), dim3(32, 8), 0, stream>>>(Tb, NU, oth, NU, 0);     // E^T
  gemm_nt<2,2,2><<<256, 256, 0, stream>>>(cur, nullptr, NU, oth, nullptr, NU,
                                  cur, NU, 1.f, 1.f, 0.f,
                                  nullptr, W11, nullptr, LDW, NU, NU, NU);       // P -> W11

  // Q = P B0^T -> W10 ;  W01 = -Q^T ;  S = I - B0 Q -> W00
  gemm_nt<2,2,2><<<256, 256, 0, stream>>>(W11, nullptr, LDW, B0h, nullptr, NU,
                                  nullptr, 0, 1.f, 0.f, 0.f,
                                  nullptr, W10, nullptr, LDW, NU, NU, NU);
  transpose_h<<<dim3(32, 32), dim3(32, 8), 0, stream>>>(W10, LDW, Tb, NU, 0);    // Q^T
  transpose_h<<<dim3(32, 32), dim3(32, 8), 0, stream>>>(W10, LDW, W01, LDW, 1);  // -Q^T
  gemm_nt<2,2,2><<<256, 256, 0, stream>>>(B0h, nullptr, NU, Tb, nullptr, NU,
                                  nullptr, 0, -1.f, 0.f, 1.f,
                                  nullptr, W00, nullptr, LDW, NU, NU, NU);

  // [x; y] = W * [z1; z2]  (2048 x 8192 x 2048), fp32 out straight into d_out
  gemm_nt<4,4,2><<<(LDW / 128) * (NB / 128), 256, 0, stream>>>(W, nullptr, LDW, zzT, nullptr, LDW,
                                  nullptr, 0, 1.f, 0.f, 0.f,
                                  out, nullptr, nullptr, NB, LDW, NB, LDW);
}

// Round 3
// 242.440 us; speedup vs baseline: 2.1287x; 1.3285x over previous
//
#include <hip/hip_runtime.h>
#include <stdint.h>

typedef unsigned short u16;
typedef __bf16 bf16x8 __attribute__((ext_vector_type(8)));
typedef float f32x4 __attribute__((ext_vector_type(4)));
typedef __attribute__((address_space(3))) void as3_void;
typedef __attribute__((address_space(1))) void as1_void;

#define NU   1024
#define NB   8192
#define LDW  2048

// Degree-2 constrained-Chebyshev init for 1/lambda on [2, 13.8]:
// X0 = D0*I + D1*M + D2*M^2, ||I - M X0|| <= 1/|T3(t(0))| = 0.179
#define D0 0.561812f
#define D1 (-0.0826391f)
#define D2 0.00348686f

// ---------- bf16 helpers (RNE, bit ops; inputs finite) ----------
__device__ __forceinline__ u16 f2h(float f) {
  union { float f; uint32_t u; } c; c.f = f;
  uint32_t r = (c.u + 0x7fffu + ((c.u >> 16) & 1u)) >> 16;
  return (u16)r;
}
__device__ __forceinline__ float h2f(u16 h) {
  union { uint32_t u; float f; } c; c.u = ((uint32_t)h) << 16;
  return c.f;
}

__device__ __forceinline__ void gload16(const u16* g, u16* l) {
  __builtin_amdgcn_global_load_lds((const as1_void*)g, (as3_void*)l, 16, 0, 0);
}

// ---------- prep: B0 -> bf16 hi/lo, plain and transposed ----------
__global__ void prep_b0(const float* __restrict__ B0, u16* __restrict__ B0h,
                        u16* __restrict__ B0l, u16* __restrict__ B0Th,
                        u16* __restrict__ B0Tl) {
  __shared__ float t[32][33];
  const int bx = blockIdx.x, by = blockIdx.y;
  const int x = threadIdx.x, y0 = threadIdx.y;
  #pragma unroll
  for (int yy = y0; yy < 32; yy += 8) {
    const int r = by * 32 + yy, c = bx * 32 + x;
    const float v = B0[(size_t)r * NU + c];
    t[yy][x] = v;
    const u16 hh = f2h(v);
    B0h[(size_t)r * NU + c] = hh;
    B0l[(size_t)r * NU + c] = f2h(v - h2f(hh));
  }
  __syncthreads();
  #pragma unroll
  for (int yy = y0; yy < 32; yy += 8) {
    const int r = bx * 32 + yy, c = by * 32 + x;  // B0T[r][c] = B0[c][r]
    const float v = t[x][yy];
    const u16 hh = f2h(v);
    B0Th[(size_t)r * NU + c] = hh;
    B0Tl[(size_t)r * NU + c] = f2h(v - h2f(hh));
  }
}

// ---------- zzT[b][i] = z1, zzT[b][i+NU] = z2 (transposed, bf16) ----------
__global__ void build_zzT(const float* __restrict__ v0, const float* __restrict__ v1,
                          const float* __restrict__ q, u16* __restrict__ zzT) {
  __shared__ u16 z1t[32][33], z2t[32][33];
  const int bx = blockIdx.x;  // batch tile
  const int by = blockIdx.y;  // unit tile
  const int x = threadIdx.x, y0 = threadIdx.y;
  #pragma unroll
  for (int yy = y0; yy < 32; yy += 8) {
    const int i = by * 32 + yy;
    const int b = bx * 32 + x;
    const float a0 = v0[(size_t)i * NB + b];
    const float a1 = v1[(size_t)i * NB + b];
    z1t[yy][x] = f2h(a0 + 0.1f * q[i]);          // z1 = v0 + DT*q
    z2t[yy][x] = f2h(a1 + tanhf(a0));            // z2 = v1 + (DT/EPS)*tanh(v0)
  }
  __syncthreads();
  #pragma unroll
  for (int yy = y0; yy < 32; yy += 8) {
    const int b = bx * 32 + yy;
    const int i = by * 32 + x;
    zzT[(size_t)b * LDW + i]      = z1t[x][yy];
    zzT[(size_t)b * LDW + NU + i] = z2t[x][yy];
  }
}

// ---------- bf16 transpose, optional negate (sign-bit flip) ----------
__global__ void transpose_h(const u16* __restrict__ in, int ldi,
                            u16* __restrict__ out, int ldo, int flip) {
  __shared__ u16 t[32][33];
  const int bx = blockIdx.x, by = blockIdx.y;
  const int x = threadIdx.x, y0 = threadIdx.y;
  #pragma unroll
  for (int yy = y0; yy < 32; yy += 8)
    t[yy][x] = in[(size_t)(by * 32 + yy) * ldi + bx * 32 + x];
  __syncthreads();
  const u16 m = flip ? (u16)0x8000u : (u16)0;
  #pragma unroll
  for (int yy = y0; yy < 32; yy += 8)
    out[(size_t)(bx * 32 + yy) * ldo + by * 32 + x] = (u16)(t[x][yy] ^ m);
}

// ---------- NT-form bf16 GEMM (small, 64x64 tile): C = A * Bt^T ----------
template<int FM, int FN, int NBUF>
__global__ __launch_bounds__(256)
void gemm_nt(const u16* __restrict__ A0, const u16* __restrict__ A1, int lda,
             const u16* __restrict__ Bt0, const u16* __restrict__ Bt1, int ldb,
             const u16* __restrict__ AUX, int ldaux,
             float alpha, float beta, float gamma,
             float* __restrict__ outF, u16* __restrict__ outH, u16* __restrict__ outL,
             int ldc, int M, int N, int K) {
  static_assert(FM == FN, "square tiles only");
  constexpr int BM = FM * 32;
  constexpr int R  = BM / 64;
  __shared__ u16 lds[NBUF][BM * 32];

  const int nTm = M / BM;
  const int nwg = (int)gridDim.x;
  int wg = (int)blockIdx.x;
  if ((nwg & 7) == 0) {
    const int c = nwg >> 3;
    wg = (wg & 7) * c + (wg >> 3);
  }
  const int tm = wg % nTm, tn = wg / nTm;
  const int row0 = tm * BM, col0 = tn * BM;

  const int tid = threadIdx.x;
  const int lane = tid & 63;
  const int wid = tid >> 6;
  const int wm = wid >> 1, wn = wid & 1;
  const int r16 = lane & 15, ch = lane >> 4;

  const bool hasA1 = (A1 != nullptr);
  const bool hasB1 = (Bt1 != nullptr);

  f32x4 acc[FM][FN] = {};

  const int nK = K >> 5;
  for (int kt = 0; kt < nK; ++kt) {
    const int k0 = kt << 5;
    #pragma unroll
    for (int h = 0; h < R; ++h) {
      const int L = tid + (h << 8);
      const int row = L >> 2, seg = L & 3;
      const int ss = seg ^ ((row >> 1) & 3);
      const size_t goffA = (size_t)(row0 + row) * lda + (size_t)(k0 + (ss << 3));
      const size_t goffB = (size_t)(col0 + row) * ldb + (size_t)(k0 + (ss << 3));
      const int dofs = (L & ~63) << 3;
      gload16(A0 + goffA, &lds[0][dofs]);
      gload16(Bt0 + goffB, &lds[1][dofs]);
      if constexpr (NBUF > 2) {
        if (hasA1) gload16(A1 + goffA, &lds[2][dofs]);
        if (hasB1) gload16(Bt1 + goffB, &lds[3][dofs]);
      }
    }
    __syncthreads();

    bf16x8 av[FM], bv[FN];
    #pragma unroll
    for (int f = 0; f < FM; ++f) {
      const int ra = wm * (FM * 16) + (f << 4) + r16;
      av[f] = *(const bf16x8*)&lds[0][(ra << 5) + ((((ch ^ (ra >> 1))) & 3) << 3)];
      const int rb = wn * (FN * 16) + (f << 4) + r16;
      bv[f] = *(const bf16x8*)&lds[1][(rb << 5) + ((((ch ^ (rb >> 1))) & 3) << 3)];
    }
    #pragma unroll
    for (int fm = 0; fm < FM; ++fm)
      #pragma unroll
      for (int fn = 0; fn < FN; ++fn)
        acc[fm][fn] = __builtin_amdgcn_mfma_f32_16x16x32_bf16(av[fm], bv[fn], acc[fm][fn], 0, 0, 0);

    if constexpr (NBUF > 2) {
      if (hasA1) {
        bf16x8 a1[FM];
        #pragma unroll
        for (int f = 0; f < FM; ++f) {
          const int ra = wm * (FM * 16) + (f << 4) + r16;
          a1[f] = *(const bf16x8*)&lds[2][(ra << 5) + ((((ch ^ (ra >> 1))) & 3) << 3)];
        }
        #pragma unroll
        for (int fm = 0; fm < FM; ++fm)
          #pragma unroll
          for (int fn = 0; fn < FN; ++fn)
            acc[fm][fn] = __builtin_amdgcn_mfma_f32_16x16x32_bf16(a1[fm], bv[fn], acc[fm][fn], 0, 0, 0);
      }
      if (hasB1) {
        bf16x8 b1[FN];
        #pragma unroll
        for (int f = 0; f < FN; ++f) {
          const int rb = wn * (FN * 16) + (f << 4) + r16;
          b1[f] = *(const bf16x8*)&lds[3][(rb << 5) + ((((ch ^ (rb >> 1))) & 3) << 3)];
        }
        #pragma unroll
        for (int fm = 0; fm < FM; ++fm)
          #pragma unroll
          for (int fn = 0; fn < FN; ++fn)
            acc[fm][fn] = __builtin_amdgcn_mfma_f32_16x16x32_bf16(av[fm], b1[fn], acc[fm][fn], 0, 0, 0);
      }
    }
    __syncthreads();
  }

  const int rbase = row0 + wm * (FM * 16) + ((lane >> 4) << 2);
  const int cbase = col0 + wn * (FN * 16) + (lane & 15);
  #pragma unroll
  for (int fm = 0; fm < FM; ++fm) {
    #pragma unroll
    for (int fn = 0; fn < FN; ++fn) {
      #pragma unroll
      for (int j = 0; j < 4; ++j) {
        const int gr = rbase + (fm << 4) + j;
        const int gc = cbase + (fn << 4);
        float v = alpha * acc[fm][fn][j];
        if (AUX) v += beta * h2f(AUX[(size_t)gr * ldaux + gc]);
        if (gamma != 0.f && gr == gc) v += gamma;
        const size_t off = (size_t)gr * ldc + gc;
        if (outF) outF[off] = v;
        if (outH) {
          const u16 hh = f2h(v);
          outH[off] = hh;
          if (outL) outL[off] = f2h(v - h2f(hh));
        }
      }
    }
  }
}

// ---------- big GEMM: 256x256 tile, BK=64, 8 waves (2x4), dbuf LDS,
// issue-early staging + counted vmcnt(8) (never 0 in-loop), raw barriers.
// C (fp32) = A (bf16 [M][K]) * Bt^T (bf16 [N][K]) ----------
__global__ __launch_bounds__(512, 2)
void gemm_big(const u16* __restrict__ A, const u16* __restrict__ Bt,
              float* __restrict__ C, int lda, int ldb, int ldc,
              int M, int N, int K) {
  __shared__ u16 Al[2][256 * 64];  // 32 KB each
  __shared__ u16 Bl[2][256 * 64];  // total 128 KB

  const int nTm = M >> 8, nTn = N >> 8;
  const int nwg = nTm * nTn;
  int wg = (int)blockIdx.x;
  { const int c = nwg >> 3; wg = (wg & 7) * c + (wg >> 3); }  // XCD swizzle (nwg%8==0)
  const int tm = wg % nTm, tn = wg / nTm;                     // tn-major
  const int row0 = tm << 8, col0 = tn << 8;

  const int tid = threadIdx.x;
  const int lane = tid & 63, wid = tid >> 6;
  const int wm = wid >> 2, wn = wid & 3;   // wave tile 128x64
  const int r16 = lane & 15, ch = lane >> 4;

  f32x4 acc[8][4] = {};

  // stage one 256x64 operand tile: 4 x gload16 per thread.
  // row = L>>3, seg = L&7; source col-chunk pre-swizzled ss = seg^(row&7);
  // LDS dest linear (wave-uniform base + lane*16B).
  auto stage = [&](const u16* __restrict__ G, int gld, int grow0, int k0, u16* lb) {
    #pragma unroll
    for (int h = 0; h < 4; ++h) {
      const int L = tid + (h << 9);
      const int row = L >> 3, seg = L & 7;
      const int ss = seg ^ (row & 7);
      gload16(G + (size_t)(grow0 + row) * gld + (size_t)(k0 + (ss << 3)),
              lb + ((L & ~63) << 3));
    }
  };

  const int nK = K >> 6;
  stage(A, lda, row0, 0, &Al[0][0]);
  stage(Bt, ldb, col0, 0, &Bl[0][0]);

  for (int t = 0; t < nK; ++t) {
    const int cur = t & 1;
    if (t + 1 < nK) {
      stage(A, lda, row0, (t + 1) << 6, &Al[cur ^ 1][0]);
      stage(Bt, ldb, col0, (t + 1) << 6, &Bl[cur ^ 1][0]);
      asm volatile("s_waitcnt vmcnt(8)" ::: "memory");  // tile t landed; t+1 in flight
    } else {
      asm volatile("s_waitcnt vmcnt(0)" ::: "memory");
    }
    __builtin_amdgcn_sched_barrier(0);
    __builtin_amdgcn_s_barrier();            // barrier A: tile t globally visible
    __builtin_amdgcn_sched_barrier(0);

    #pragma unroll
    for (int kk = 0; kk < 2; ++kk) {
      bf16x8 av[8], bv[4];
      #pragma unroll
      for (int f = 0; f < 8; ++f) {
        const int ra = (wm << 7) + (f << 4) + r16;
        const int sa = ((kk << 2) + ch) ^ (ra & 7);
        av[f] = *(const bf16x8*)&Al[cur][(ra << 6) + (sa << 3)];
      }
      #pragma unroll
      for (int f = 0; f < 4; ++f) {
        const int rb = (wn << 6) + (f << 4) + r16;
        const int sb = ((kk << 2) + ch) ^ (rb & 7);
        bv[f] = *(const bf16x8*)&Bl[cur][(rb << 6) + (sb << 3)];
      }
      __builtin_amdgcn_s_setprio(1);
      #pragma unroll
      for (int fm = 0; fm < 8; ++fm)
        #pragma unroll
        for (int fn = 0; fn < 4; ++fn)
          acc[fm][fn] = __builtin_amdgcn_mfma_f32_16x16x32_bf16(av[fm], bv[fn], acc[fm][fn], 0, 0, 0);
      __builtin_amdgcn_s_setprio(0);
    }
    __builtin_amdgcn_sched_barrier(0);
    __builtin_amdgcn_s_barrier();            // barrier B: reads done before next stage overwrites
    __builtin_amdgcn_sched_barrier(0);
  }

  const int rbase = row0 + (wm << 7) + ((lane >> 4) << 2);
  const int cbase = col0 + (wn << 6) + (lane & 15);
  #pragma unroll
  for (int fm = 0; fm < 8; ++fm)
    #pragma unroll
    for (int fn = 0; fn < 4; ++fn)
      #pragma unroll
      for (int j = 0; j < 4; ++j) {
        const int gr = rbase + (fm << 4) + j;
        const int gc = cbase + (fn << 4);
        C[(size_t)gr * ldc + gc] = acc[fm][fn][j];
      }
}

extern "C" void kernel_launch(void* const* d_in, const int* in_sizes, int n_in,
                              void* d_out, int out_size, void* d_ws, size_t ws_size,
                              hipStream_t stream) {
  (void)in_sizes; (void)n_in; (void)out_size; (void)ws_size;
  const float* v0 = (const float*)d_in[0];
  const float* v1 = (const float*)d_in[1];
  const float* B0 = (const float*)d_in[2];
  const float* q  = (const float*)d_in[3];
  float* out = (float*)d_out;

  size_t off = 0;
  char* base = (char*)d_ws;
  auto alloc = [&](size_t bytes) -> u16* {
    char* r = base + off;
    off += (bytes + 255) & ~(size_t)255;
    return (u16*)r;
  };
  u16* zzT  = alloc((size_t)NB * LDW * 2);   // 33.6 MB
  u16* W    = alloc((size_t)LDW * LDW * 2);  //  8.4 MB
  u16* B0h  = alloc((size_t)NU * NU * 2);
  u16* B0l  = alloc((size_t)NU * NU * 2);
  u16* B0Th = alloc((size_t)NU * NU * 2);
  u16* B0Tl = alloc((size_t)NU * NU * 2);
  u16* Mh   = alloc((size_t)NU * NU * 2);
  u16* Ml   = alloc((size_t)NU * NU * 2);
  u16* X0b  = alloc((size_t)NU * NU * 2);
  u16* X1b  = alloc((size_t)NU * NU * 2);
  u16* Tb   = alloc((size_t)NU * NU * 2);
  u16* Xt   = alloc((size_t)NU * NU * 2);

  u16* W00 = W;
  u16* W01 = W + NU;
  u16* W10 = W + (size_t)NU * LDW;
  u16* W11 = W + (size_t)NU * LDW + NU;

  prep_b0<<<dim3(32, 32), dim3(32, 8), 0, stream>>>(B0, B0h, B0l, B0Th, B0Tl);
  build_zzT<<<dim3(NB / 32, NU / 32), dim3(32, 8), 0, stream>>>(v0, v1, q, zzT);

  // M = 2I + B0^T B0 in split precision (hh + lh + hl), emitted as Mh+Ml
  gemm_nt<2,2,4><<<256, 256, 0, stream>>>(B0Th, B0Tl, NU, B0Th, B0Tl, NU,
                                  nullptr, 0, 1.f, 0.f, 2.f,
                                  nullptr, Mh, Ml, NU, NU, NU, NU);

  // X0 = D2*M^2 + D1*M + D0*I (degree-2 Chebyshev init, e=0.179)
  gemm_nt<2,2,2><<<256, 256, 0, stream>>>(Mh, nullptr, NU, Mh, nullptr, NU,
                                  Mh, NU, D2, D1, D0,
                                  nullptr, X0b, nullptr, NU, NU, NU, NU);

  // one Newton-Schulz step: X1 = 2*X0 - X0*(M*X0)   (e -> 0.032)
  gemm_nt<2,2,2><<<256, 256, 0, stream>>>(Mh, nullptr, NU, X0b, nullptr, NU,
                                  nullptr, 0, 1.f, 0.f, 0.f,
                                  nullptr, Tb, nullptr, NU, NU, NU, NU);       // T = M X0^T
  gemm_nt<2,2,2><<<256, 256, 0, stream>>>(X0b, nullptr, NU, Tb, nullptr, NU,
                                  X0b, NU, -1.f, 2.f, 0.f,
                                  nullptr, X1b, nullptr, NU, NU, NU, NU);      // X1 = 2X0 - X0 T^T

  // exact residual refinement: E = I - M*X1 (split M), X <- X1 + X1*E
  transpose_h<<<dim3(32, 32), dim3(32, 8), 0, stream>>>(X1b, NU, Xt, NU, 0);   // X1^T
  gemm_nt<2,2,4><<<256, 256, 0, stream>>>(Mh, Ml, NU, Xt, nullptr, NU,
                                  nullptr, 0, -1.f, 0.f, 1.f,
                                  nullptr, Tb, nullptr, NU, NU, NU, NU);       // E = I - M X1
  transpose_h<<<dim3(32, 32), dim3(32, 8), 0, stream>>>(Tb, NU, X0b, NU, 0);   // E^T
  gemm_nt<2,2,2><<<256, 256, 0, stream>>>(X1b, nullptr, NU, X0b, nullptr, NU,
                                  X1b, NU, 1.f, 1.f, 0.f,
                                  nullptr, W11, nullptr, LDW, NU, NU, NU);     // P -> W11

  // Q = P B0^T -> W10 ;  W01 = -Q^T ;  S = I - B0 Q -> W00
  gemm_nt<2,2,2><<<256, 256, 0, stream>>>(W11, nullptr, LDW, B0h, nullptr, NU,
                                  nullptr, 0, 1.f, 0.f, 0.f,
                                  nullptr, W10, nullptr, LDW, NU, NU, NU);
  transpose_h<<<dim3(32, 32), dim3(32, 8), 0, stream>>>(W10, LDW, Tb, NU, 0);  // Q^T
  transpose_h<<<dim3(32, 32), dim3(32, 8), 0, stream>>>(W10, LDW, W01, LDW, 1);// -Q^T
  gemm_nt<2,2,2><<<256, 256, 0, stream>>>(B0h, nullptr, NU, Tb, nullptr, NU,
                                  nullptr, 0, -1.f, 0.f, 1.f,
                                  nullptr, W00, nullptr, LDW, NU, NU, NU);

  // [x; y] = W * [z1; z2]  (2048 x 8192 x 2048), fp32 out straight into d_out
  gemm_big<<<(LDW / 256) * (NB / 256), 512, 0, stream>>>(W, zzT, out,
                                  LDW, LDW, NB, LDW, NB, LDW);
}

// Round 4
// 236.758 us; speedup vs baseline: 2.1798x; 1.0240x over previous
//
#include <hip/hip_runtime.h>
#include <stdint.h>

typedef unsigned short u16;
typedef __bf16 bf16x8 __attribute__((ext_vector_type(8)));
typedef float f32x4 __attribute__((ext_vector_type(4)));
typedef __attribute__((address_space(3))) void as3_void;
typedef __attribute__((address_space(1))) void as1_void;

#define NU   1024
#define NB   8192

// Degree-4 constrained-Chebyshev init for 1/lambda on [2, 13.8]:
// r(l) = T5(t(l))/T5(t0), e0 = 1/27.535 = 0.0363
// X0 = C0*I + C1*M + M^2*(C2*I + C3*M + C4*M^2)
#define C0 0.9513167f
#define C1 (-0.3169175f)
#define C2 0.0471891f
#define C3 (-0.00321059f)
#define C4 0.00008127825f

// ---------- bf16 helpers (RNE, bit ops; inputs finite) ----------
__device__ __forceinline__ u16 f2h(float f) {
  union { float f; uint32_t u; } c; c.f = f;
  uint32_t r = (c.u + 0x7fffu + ((c.u >> 16) & 1u)) >> 16;
  return (u16)r;
}
__device__ __forceinline__ float h2f(u16 h) {
  union { uint32_t u; float f; } c; c.u = ((uint32_t)h) << 16;
  return c.f;
}

__device__ __forceinline__ void gload16(const u16* g, u16* l) {
  __builtin_amdgcn_global_load_lds((const as1_void*)g, (as3_void*)l, 16, 0, 0);
}

// ---------- prep: B0 -> bf16 B0h (plain hi), B0Th/B0Tl (transposed hi/lo) ----------
__global__ void prep_b0(const float* __restrict__ B0, u16* __restrict__ B0h,
                        u16* __restrict__ B0Th, u16* __restrict__ B0Tl) {
  __shared__ float t[32][33];
  const int bx = blockIdx.x, by = blockIdx.y;
  const int x = threadIdx.x, y0 = threadIdx.y;
  #pragma unroll
  for (int yy = y0; yy < 32; yy += 8) {
    const int r = by * 32 + yy, c = bx * 32 + x;
    const float v = B0[(size_t)r * NU + c];
    t[yy][x] = v;
    B0h[(size_t)r * NU + c] = f2h(v);
  }
  __syncthreads();
  #pragma unroll
  for (int yy = y0; yy < 32; yy += 8) {
    const int r = bx * 32 + yy, c = by * 32 + x;  // B0T[r][c] = B0[c][r]
    const float v = t[x][yy];
    const u16 hh = f2h(v);
    B0Th[(size_t)r * NU + c] = hh;
    B0Tl[(size_t)r * NU + c] = f2h(v - h2f(hh));
  }
}

// ---------- z1T[b][i] = bf16(v0[i][b] + 0.1*q[i]) ----------
__global__ void build_z1T(const float* __restrict__ v0, const float* __restrict__ q,
                          u16* __restrict__ z1T) {
  __shared__ u16 s[32][33];
  const int bx = blockIdx.x;  // batch tile
  const int by = blockIdx.y;  // unit tile
  const int x = threadIdx.x, y0 = threadIdx.y;
  #pragma unroll
  for (int yy = y0; yy < 32; yy += 8) {
    const int i = by * 32 + yy;
    const int b = bx * 32 + x;
    s[yy][x] = f2h(v0[(size_t)i * NB + b] + 0.1f * q[i]);
  }
  __syncthreads();
  #pragma unroll
  for (int yy = y0; yy < 32; yy += 8) {
    const int b = bx * 32 + yy;
    const int i = by * 32 + x;
    z1T[(size_t)b * NU + i] = s[x][yy];
  }
}

// ---------- bf16 transpose ----------
__global__ void transpose_h(const u16* __restrict__ in, u16* __restrict__ out) {
  __shared__ u16 t[32][33];
  const int bx = blockIdx.x, by = blockIdx.y;
  const int x = threadIdx.x, y0 = threadIdx.y;
  #pragma unroll
  for (int yy = y0; yy < 32; yy += 8)
    t[yy][x] = in[(size_t)(by * 32 + yy) * NU + bx * 32 + x];
  __syncthreads();
  #pragma unroll
  for (int yy = y0; yy < 32; yy += 8)
    out[(size_t)(bx * 32 + yy) * NU + by * 32 + x] = t[x][yy];
}

// ---------- G = C2*I + C3*M + C4*M2 (elementwise, bf16) ----------
__global__ void build_g(const u16* __restrict__ Mh, const u16* __restrict__ M2,
                        u16* __restrict__ G) {
  const int idx = blockIdx.x * 256 + threadIdx.x;
  const int i = idx >> 10, j = idx & 1023;
  const float v = C3 * h2f(Mh[idx]) + C4 * h2f(M2[idx]) + ((i == j) ? C2 : 0.f);
  G[idx] = f2h(v);
}

// ---------- NT-form bf16 GEMM (small, 64x64 tile): C = A * Bt^T ----------
// Products: A0*Bt0^T (+ A1*Bt0^T if A1) (+ A0*Bt1^T if Bt1) (NBUF=4).
// Epilogue: v = alpha*acc + beta*AUX + gamma*I; outH (+outL hi/lo split).
template<int NBUF>
__global__ __launch_bounds__(256)
void gemm_nt(const u16* __restrict__ A0, const u16* __restrict__ A1,
             const u16* __restrict__ Bt0, const u16* __restrict__ Bt1,
             const u16* __restrict__ AUX,
             float alpha, float beta, float gamma,
             u16* __restrict__ outH, u16* __restrict__ outL) {
  __shared__ u16 lds[NBUF][64 * 32];

  const int nTm = 16;  // 1024/64
  int wg = (int)blockIdx.x;
  { const int c = 256 >> 3; wg = (wg & 7) * c + (wg >> 3); }
  const int tm = wg % nTm, tn = wg / nTm;
  const int row0 = tm * 64, col0 = tn * 64;

  const int tid = threadIdx.x;
  const int lane = tid & 63;
  const int wid = tid >> 6;
  const int wm = wid >> 1, wn = wid & 1;
  const int r16 = lane & 15, ch = lane >> 4;

  const bool hasA1 = (A1 != nullptr);
  const bool hasB1 = (Bt1 != nullptr);

  f32x4 acc[2][2] = {};

  for (int kt = 0; kt < 32; ++kt) {
    const int k0 = kt << 5;
    {
      const int L = tid;
      const int row = L >> 2, seg = L & 3;
      const int ss = seg ^ ((row >> 1) & 3);
      const size_t goffA = (size_t)(row0 + row) * NU + (size_t)(k0 + (ss << 3));
      const size_t goffB = (size_t)(col0 + row) * NU + (size_t)(k0 + (ss << 3));
      const int dofs = (L & ~63) << 3;
      gload16(A0 + goffA, &lds[0][dofs]);
      gload16(Bt0 + goffB, &lds[1][dofs]);
      if constexpr (NBUF > 2) {
        if (hasA1) gload16(A1 + goffA, &lds[2][dofs]);
        if (hasB1) gload16(Bt1 + goffB, &lds[3][dofs]);
      }
    }
    __syncthreads();

    bf16x8 av[2], bv[2];
    #pragma unroll
    for (int f = 0; f < 2; ++f) {
      const int ra = wm * 32 + (f << 4) + r16;
      av[f] = *(const bf16x8*)&lds[0][(ra << 5) + ((((ch ^ (ra >> 1))) & 3) << 3)];
      const int rb = wn * 32 + (f << 4) + r16;
      bv[f] = *(const bf16x8*)&lds[1][(rb << 5) + ((((ch ^ (rb >> 1))) & 3) << 3)];
    }
    #pragma unroll
    for (int fm = 0; fm < 2; ++fm)
      #pragma unroll
      for (int fn = 0; fn < 2; ++fn)
        acc[fm][fn] = __builtin_amdgcn_mfma_f32_16x16x32_bf16(av[fm], bv[fn], acc[fm][fn], 0, 0, 0);

    if constexpr (NBUF > 2) {
      if (hasA1) {
        bf16x8 a1[2];
        #pragma unroll
        for (int f = 0; f < 2; ++f) {
          const int ra = wm * 32 + (f << 4) + r16;
          a1[f] = *(const bf16x8*)&lds[2][(ra << 5) + ((((ch ^ (ra >> 1))) & 3) << 3)];
        }
        #pragma unroll
        for (int fm = 0; fm < 2; ++fm)
          #pragma unroll
          for (int fn = 0; fn < 2; ++fn)
            acc[fm][fn] = __builtin_amdgcn_mfma_f32_16x16x32_bf16(a1[fm], bv[fn], acc[fm][fn], 0, 0, 0);
      }
      if (hasB1) {
        bf16x8 b1[2];
        #pragma unroll
        for (int f = 0; f < 2; ++f) {
          const int rb = wn * 32 + (f << 4) + r16;
          b1[f] = *(const bf16x8*)&lds[3][(rb << 5) + ((((ch ^ (rb >> 1))) & 3) << 3)];
        }
        #pragma unroll
        for (int fm = 0; fm < 2; ++fm)
          #pragma unroll
          for (int fn = 0; fn < 2; ++fn)
            acc[fm][fn] = __builtin_amdgcn_mfma_f32_16x16x32_bf16(av[fm], b1[fn], acc[fm][fn], 0, 0, 0);
      }
    }
    __syncthreads();
  }

  const int rbase = row0 + wm * 32 + ((lane >> 4) << 2);
  const int cbase = col0 + wn * 32 + (lane & 15);
  #pragma unroll
  for (int fm = 0; fm < 2; ++fm)
    #pragma unroll
    for (int fn = 0; fn < 2; ++fn)
      #pragma unroll
      for (int j = 0; j < 4; ++j) {
        const int gr = rbase + (fm << 4) + j;
        const int gc = cbase + (fn << 4);
        float v = alpha * acc[fm][fn][j];
        if (AUX) v += beta * h2f(AUX[(size_t)gr * NU + gc]);
        if (gamma != 0.f && gr == gc) v += gamma;
        const size_t off = (size_t)gr * NU + gc;
        const u16 hh = f2h(v);
        outH[off] = hh;
        if (outL) outL[off] = f2h(v - h2f(hh));
      }
}

// ---------- big GEMM: TM x TN tile, BK=64, 8 waves (WRxWC), wave tile 64x64,
// dbuf LDS, issue-early staging + counted vmcnt(6). C = A * Bt^T.
// EPI 0: outF = acc                          (y = P t1)
// EPI 1: outF = p0[gr][gc] + 0.1*qv[gr]-acc  (x = z1 - R t1)
// EPI 2: outH = bf16(acc + p1^T + tanh(p0^T)) (t1T = z1T B0 + z2T) ----------
template<int TM, int TN, int WR, int WC, int EPI>
__global__ __launch_bounds__(512, 1)
void gemm_big(const u16* __restrict__ A, const u16* __restrict__ Bt,
              int lda, int ldb,
              const float* __restrict__ p0, const float* __restrict__ p1,
              const float* __restrict__ qv,
              float* __restrict__ outF, u16* __restrict__ outH, int ldc,
              int M, int N, int K) {
  constexpr int LA = TM / 64;
  constexpr int LB = TN / 64;
  static_assert(LA + LB == 6, "vmcnt literal assumes 6 loads/tile");
  static_assert(WR * WC == 8 && TM == WR * 64 && TN == WC * 64, "geometry");
  __shared__ u16 Al[2][TM * 64];
  __shared__ u16 Bl[2][TN * 64];

  const int nTm = M / TM;
  int wg = (int)blockIdx.x;
  { const int c = (int)gridDim.x >> 3; wg = (wg & 7) * c + (wg >> 3); }
  const int tm = wg % nTm, tn = wg / nTm;
  const int row0 = tm * TM, col0 = tn * TN;

  const int tid = threadIdx.x;
  const int lane = tid & 63, wid = tid >> 6;
  const int wm = wid / WC, wn = wid % WC;
  const int r16 = lane & 15, ch = lane >> 4;

  f32x4 acc[4][4] = {};

  auto stageA = [&](int k0, u16* lb) {
    #pragma unroll
    for (int h = 0; h < LA; ++h) {
      const int L = tid + (h << 9);
      const int row = L >> 3, seg = L & 7;
      const int ss = seg ^ (row & 7);
      gload16(A + (size_t)(row0 + row) * lda + (size_t)(k0 + (ss << 3)),
              lb + ((L & ~63) << 3));
    }
  };
  auto stageB = [&](int k0, u16* lb) {
    #pragma unroll
    for (int h = 0; h < LB; ++h) {
      const int L = tid + (h << 9);
      const int row = L >> 3, seg = L & 7;
      const int ss = seg ^ (row & 7);
      gload16(Bt + (size_t)(col0 + row) * ldb + (size_t)(k0 + (ss << 3)),
              lb + ((L & ~63) << 3));
    }
  };

  const int nK = K >> 6;
  stageA(0, &Al[0][0]);
  stageB(0, &Bl[0][0]);

  for (int t = 0; t < nK; ++t) {
    const int cur = t & 1;
    if (t + 1 < nK) {
      stageA((t + 1) << 6, &Al[cur ^ 1][0]);
      stageB((t + 1) << 6, &Bl[cur ^ 1][0]);
      asm volatile("s_waitcnt vmcnt(6)" ::: "memory");  // tile t landed; t+1 in flight
    } else {
      asm volatile("s_waitcnt vmcnt(0)" ::: "memory");
    }
    __builtin_amdgcn_sched_barrier(0);
    __builtin_amdgcn_s_barrier();
    __builtin_amdgcn_sched_barrier(0);

    #pragma unroll
    for (int kk = 0; kk < 2; ++kk) {
      bf16x8 av[4], bv[4];
      #pragma unroll
      for (int f = 0; f < 4; ++f) {
        const int ra = (wm << 6) + (f << 4) + r16;
        const int sa = ((kk << 2) + ch) ^ (ra & 7);
        av[f] = *(const bf16x8*)&Al[cur][(ra << 6) + (sa << 3)];
        const int rb = (wn << 6) + (f << 4) + r16;
        const int sb = ((kk << 2) + ch) ^ (rb & 7);
        bv[f] = *(const bf16x8*)&Bl[cur][(rb << 6) + (sb << 3)];
      }
      __builtin_amdgcn_s_setprio(1);
      #pragma unroll
      for (int fm = 0; fm < 4; ++fm)
        #pragma unroll
        for (int fn = 0; fn < 4; ++fn)
          acc[fm][fn] = __builtin_amdgcn_mfma_f32_16x16x32_bf16(av[fm], bv[fn], acc[fm][fn], 0, 0, 0);
      __builtin_amdgcn_s_setprio(0);
    }
    __builtin_amdgcn_sched_barrier(0);
    __builtin_amdgcn_s_barrier();
    __builtin_amdgcn_sched_barrier(0);
  }

  const int rbase = row0 + (wm << 6) + ((lane >> 4) << 2);
  const int cbase = col0 + (wn << 6) + (lane & 15);
  #pragma unroll
  for (int fm = 0; fm < 4; ++fm)
    #pragma unroll
    for (int fn = 0; fn < 4; ++fn)
      #pragma unroll
      for (int j = 0; j < 4; ++j) {
        const int gr = rbase + (fm << 4) + j;
        const int gc = cbase + (fn << 4);
        if constexpr (EPI == 0) {
          outF[(size_t)gr * ldc + gc] = acc[fm][fn][j];
        } else if constexpr (EPI == 1) {
          outF[(size_t)gr * ldc + gc] =
              p0[(size_t)gr * NB + gc] + 0.1f * qv[gr] - acc[fm][fn][j];
        } else {
          const float z2 = p1[(size_t)gc * NB + gr] + tanhf(p0[(size_t)gc * NB + gr]);
          outH[(size_t)gr * ldc + gc] = f2h(acc[fm][fn][j] + z2);
        }
      }
}

extern "C" void kernel_launch(void* const* d_in, const int* in_sizes, int n_in,
                              void* d_out, int out_size, void* d_ws, size_t ws_size,
                              hipStream_t stream) {
  (void)in_sizes; (void)n_in; (void)out_size; (void)ws_size;
  const float* v0 = (const float*)d_in[0];
  const float* v1 = (const float*)d_in[1];
  const float* B0 = (const float*)d_in[2];
  const float* q  = (const float*)d_in[3];
  float* out = (float*)d_out;

  size_t off = 0;
  char* base = (char*)d_ws;
  auto alloc = [&](size_t bytes) -> u16* {
    char* r = base + off;
    off += (bytes + 255) & ~(size_t)255;
    return (u16*)r;
  };
  u16* z1T  = alloc((size_t)NB * NU * 2);  // 16.8 MB
  u16* t1T  = alloc((size_t)NB * NU * 2);  // 16.8 MB
  u16* B0h  = alloc((size_t)NU * NU * 2);
  u16* B0Th = alloc((size_t)NU * NU * 2);
  u16* B0Tl = alloc((size_t)NU * NU * 2);
  u16* Mh   = alloc((size_t)NU * NU * 2);
  u16* Ml   = alloc((size_t)NU * NU * 2);
  u16* S1   = alloc((size_t)NU * NU * 2);
  u16* S2   = alloc((size_t)NU * NU * 2);
  u16* S3   = alloc((size_t)NU * NU * 2);   // total ~50 MB

  prep_b0<<<dim3(32, 32), dim3(32, 8), 0, stream>>>(B0, B0h, B0Th, B0Tl);
  build_z1T<<<dim3(NB / 32, NU / 32), dim3(32, 8), 0, stream>>>(v0, q, z1T);

  // M = 2I + B0^T B0 in split precision (hh + lh + hl) -> Mh + Ml
  gemm_nt<4><<<256, 256, 0, stream>>>(B0Th, B0Tl, B0Th, B0Tl,
                                      nullptr, 1.f, 0.f, 2.f, Mh, Ml);
  // M2 = M*M (symmetric)
  gemm_nt<2><<<256, 256, 0, stream>>>(Mh, nullptr, Mh, nullptr,
                                      nullptr, 1.f, 0.f, 0.f, S1, nullptr);
  // G = C2 I + C3 M + C4 M2
  build_g<<<NU * NU / 256, 256, 0, stream>>>(Mh, S1, S2);
  // X0 = M2*G + C1*M + C0*I  (deg-4 Chebyshev, e0 = 0.036)
  gemm_nt<2><<<256, 256, 0, stream>>>(S1, nullptr, S2, nullptr,
                                      Mh, 1.f, C1, C0, S3, nullptr);
  // exact residual refinement: E = I - M*X0 (split M), P = X0 + X0*E
  transpose_h<<<dim3(32, 32), dim3(32, 8), 0, stream>>>(S3, S2);          // X0^T
  gemm_nt<4><<<256, 256, 0, stream>>>(Mh, Ml, S2, nullptr,
                                      nullptr, -1.f, 0.f, 1.f, S1, nullptr);  // E
  transpose_h<<<dim3(32, 32), dim3(32, 8), 0, stream>>>(S1, S2);          // E^T
  gemm_nt<2><<<256, 256, 0, stream>>>(S3, nullptr, S2, nullptr,
                                      S3, 1.f, 1.f, 0.f, Ml, nullptr);    // P -> Ml slot
  // R = B0 * P (P symmetric)
  gemm_nt<2><<<256, 256, 0, stream>>>(B0h, nullptr, Ml, nullptr,
                                      nullptr, 1.f, 0.f, 0.f, Mh, nullptr); // R -> Mh slot

  // apply:
  // A) t1T[b][i] = sum_k z1T[b][k] B0[k][i] + v1[i][b] + tanh(v0[i][b])
  gemm_big<256, 128, 4, 2, 2><<<256, 512, 0, stream>>>(
      z1T, B0Th, NU, NU, v0, v1, nullptr, nullptr, t1T, NU, NB, NU, NU);
  // B) y = P * t1  -> out rows 1024..2047
  gemm_big<128, 256, 2, 4, 0><<<256, 512, 0, stream>>>(
      Ml, t1T, NU, NU, nullptr, nullptr, nullptr,
      out + (size_t)NU * NB, nullptr, NB, NU, NB, NU);
  // C) x = z1 - R * t1 = v0 + 0.1 q - R*t1 -> out rows 0..1023
  gemm_big<128, 256, 2, 4, 1><<<256, 512, 0, stream>>>(
      Mh, t1T, NU, NU, v0, nullptr, q,
      out, nullptr, NB, NU, NB, NU);
}

// Round 5
// 231.639 us; speedup vs baseline: 2.2279x; 1.0221x over previous
//
#include <hip/hip_runtime.h>
#include <stdint.h>

typedef unsigned short u16;
typedef __bf16 bf16x8 __attribute__((ext_vector_type(8)));
typedef float f32x4 __attribute__((ext_vector_type(4)));
typedef __attribute__((address_space(3))) void as3_void;
typedef __attribute__((address_space(1))) void as1_void;

#define NU   1024
#define NBB  8192

// Degree-4 constrained-Chebyshev init for 1/lambda on [2, 13.8]:
// X0 = C0*I + C1*M + M^2*(C2*I + C3*M + C4*M^2), e0 = 0.0363
#define C0 0.9513167f
#define C1 (-0.3169175f)
#define C2 0.0471891f
#define C3 (-0.00321059f)
#define C4 0.00008127825f

// ---------- bf16 helpers (RNE, bit ops; inputs finite) ----------
__device__ __forceinline__ u16 f2h(float f) {
  union { float f; uint32_t u; } c; c.f = f;
  uint32_t r = (c.u + 0x7fffu + ((c.u >> 16) & 1u)) >> 16;
  return (u16)r;
}
__device__ __forceinline__ float h2f(u16 h) {
  union { uint32_t u; float f; } c; c.u = ((uint32_t)h) << 16;
  return c.f;
}

__device__ __forceinline__ void gload16(const u16* g, u16* l) {
  __builtin_amdgcn_global_load_lds((const as1_void*)g, (as3_void*)l, 16, 0, 0);
}

// ---------- prep: B0 -> bf16 B0h (plain hi), B0Th/B0Tl (transposed hi/lo) ----------
__global__ void prep_b0(const float* __restrict__ B0, u16* __restrict__ B0h,
                        u16* __restrict__ B0Th, u16* __restrict__ B0Tl) {
  __shared__ float t[32][33];
  const int bx = blockIdx.x, by = blockIdx.y;
  const int x = threadIdx.x, y0 = threadIdx.y;
  #pragma unroll
  for (int yy = y0; yy < 32; yy += 8) {
    const int r = by * 32 + yy, c = bx * 32 + x;
    const float v = B0[(size_t)r * NU + c];
    t[yy][x] = v;
    B0h[(size_t)r * NU + c] = f2h(v);
  }
  __syncthreads();
  #pragma unroll
  for (int yy = y0; yy < 32; yy += 8) {
    const int r = bx * 32 + yy, c = by * 32 + x;  // B0T[r][c] = B0[c][r]
    const float v = t[x][yy];
    const u16 hh = f2h(v);
    B0Th[(size_t)r * NU + c] = hh;
    B0Tl[(size_t)r * NU + c] = f2h(v - h2f(hh));
  }
}

// ---------- z1T[b][i] = bf16(v0[i][b]+0.1q[i]);  z2T[b][i] = bf16(v1[i][b]+tanh(v0[i][b])) ----------
__global__ void build_zT(const float* __restrict__ v0, const float* __restrict__ v1,
                         const float* __restrict__ q,
                         u16* __restrict__ z1T, u16* __restrict__ z2T) {
  __shared__ u16 s1[32][33], s2[32][33];
  const int bx = blockIdx.x;  // batch tile
  const int by = blockIdx.y;  // unit tile
  const int x = threadIdx.x, y0 = threadIdx.y;
  #pragma unroll
  for (int yy = y0; yy < 32; yy += 8) {
    const int i = by * 32 + yy;
    const int b = bx * 32 + x;
    const float a0 = v0[(size_t)i * NBB + b];
    const float a1 = v1[(size_t)i * NBB + b];
    s1[yy][x] = f2h(a0 + 0.1f * q[i]);
    s2[yy][x] = f2h(a1 + tanhf(a0));
  }
  __syncthreads();
  #pragma unroll
  for (int yy = y0; yy < 32; yy += 8) {
    const int b = bx * 32 + yy;
    const int i = by * 32 + x;
    z1T[(size_t)b * NU + i] = s1[x][yy];
    z2T[(size_t)b * NU + i] = s2[x][yy];
  }
}

// ---------- bf16 1024x1024 transpose ----------
__global__ void transpose_h(const u16* __restrict__ in, u16* __restrict__ out) {
  __shared__ u16 t[32][33];
  const int bx = blockIdx.x, by = blockIdx.y;
  const int x = threadIdx.x, y0 = threadIdx.y;
  #pragma unroll
  for (int yy = y0; yy < 32; yy += 8)
    t[yy][x] = in[(size_t)(by * 32 + yy) * NU + bx * 32 + x];
  __syncthreads();
  #pragma unroll
  for (int yy = y0; yy < 32; yy += 8)
    out[(size_t)(bx * 32 + yy) * NU + by * 32 + x] = t[x][yy];
}

// ---------- G = C2*I + C3*M + C4*M2 (elementwise, bf16) ----------
__global__ void build_g(const u16* __restrict__ Mh, const u16* __restrict__ M2,
                        u16* __restrict__ G) {
  const int idx = blockIdx.x * 256 + threadIdx.x;
  const int i = idx >> 10, j = idx & 1023;
  const float v = C3 * h2f(Mh[idx]) + C4 * h2f(M2[idx]) + ((i == j) ? C2 : 0.f);
  G[idx] = f2h(v);
}

// ---------- unified pipelined NT GEMM: C = A * Bt^T ----------
// A [M][K], Bt [N][K], both K-contiguous bf16. Tile TM x TN, WRxWC waves
// (64x64... wave tiles), BK=64, double-buffered LDS, issue-early staging,
// counted vmcnt (never 0 in main loop), setprio around MFMA clusters.
// NOPS: 2 = {A0,B0}; 3 = +A1 (dual-A: (A0+A1)*B0); 4 = +B1 (split: A0B0+A1B0+A0B1).
// EPI 0: outH(+outL) = bf16split(alpha*acc + beta*auxH + gamma*I)   [setup]
// EPI 1: outH = bf16(acc + auxH)                                    [t1T]
// EPI 2: outF = gr<NU ? auxF + 0.1*qv[gr] - acc : acc; A-ptr select [x;y]
template<int TM, int TN, int WR, int WC, int NOPS, int EPI>
__global__ __launch_bounds__(WR * WC * 64, 1)
void gemm_u(const u16* __restrict__ A0, const u16* __restrict__ A1,
            const u16* __restrict__ Bt0, const u16* __restrict__ Bt1,
            int lda, int ldb,
            const u16* __restrict__ auxH, const float* __restrict__ auxF,
            const float* __restrict__ qv,
            float alpha, float beta, float gamma,
            float* __restrict__ outF, u16* __restrict__ outH, u16* __restrict__ outL,
            int ldc, int M, int N, int K) {
  constexpr int NTHR = WR * WC * 64;
  constexpr int RA = 8 * TM / NTHR;   // staging rounds per A buffer
  constexpr int RB = 8 * TN / NTHR;
  constexpr int NA = (NOPS >= 3) ? 2 : 1;
  constexpr int NB2 = (NOPS == 4) ? 2 : 1;
  constexpr int LOADS = RA * NA + RB * NB2;
  constexpr int FM = TM / (WR * 16);
  constexpr int FN = TN / (WC * 16);
  static_assert(LOADS == 4 || LOADS == 6 || LOADS == 8, "vmcnt dispatch");
  __shared__ u16 Al[2][NA][TM * 64];
  __shared__ u16 Bl[2][NB2][TN * 64];

  const int nTm = M / TM;
  int wg = (int)blockIdx.x;
  { const int c = (int)gridDim.x >> 3; wg = (wg & 7) * c + (wg >> 3); }  // XCD swizzle
  const int tm = wg % nTm, tn = wg / nTm;
  const int row0 = tm * TM, col0 = tn * TN;

  // EPI 2: stacked A = [R; P] via pointer select (rows never straddle NU)
  const u16* Aur = A0;
  int row0A = row0;
  if constexpr (EPI == 2) {
    if (row0 >= NU) { Aur = A1; row0A = row0 - NU; }
  }

  const int tid = threadIdx.x;
  const int lane = tid & 63, wid = tid >> 6;
  const int wm = wid / WC, wn = wid % WC;
  const int r16 = lane & 15, ch = lane >> 4;

  f32x4 acc[FM][FN] = {};

  auto stageAll = [&](int k0, int buf) {
    #pragma unroll
    for (int h = 0; h < RA; ++h) {
      const int L = tid + h * NTHR;
      const int row = L >> 3;
      const int ss = (L & 7) ^ (row & 7);
      const size_t go = (size_t)(row0A + row) * lda + (size_t)(k0 + (ss << 3));
      gload16(Aur + go, &Al[buf][0][(L & ~63) << 3]);
      if constexpr (NA == 2 && EPI != 2) gload16(A1 + go, &Al[buf][1][(L & ~63) << 3]);
    }
    #pragma unroll
    for (int h = 0; h < RB; ++h) {
      const int L = tid + h * NTHR;
      const int row = L >> 3;
      const int ss = (L & 7) ^ (row & 7);
      const size_t go = (size_t)(col0 + row) * ldb + (size_t)(k0 + (ss << 3));
      gload16(Bt0 + go, &Bl[buf][0][(L & ~63) << 3]);
      if constexpr (NB2 == 2) gload16(Bt1 + go, &Bl[buf][1][(L & ~63) << 3]);
    }
  };

  const int nK = K >> 6;
  stageAll(0, 0);

  for (int t = 0; t < nK; ++t) {
    const int cur = t & 1;
    if (t + 1 < nK) {
      stageAll((t + 1) << 6, cur ^ 1);
      if constexpr (LOADS == 4) asm volatile("s_waitcnt vmcnt(4)" ::: "memory");
      else if constexpr (LOADS == 6) asm volatile("s_waitcnt vmcnt(6)" ::: "memory");
      else asm volatile("s_waitcnt vmcnt(8)" ::: "memory");
    } else {
      asm volatile("s_waitcnt vmcnt(0)" ::: "memory");
    }
    __builtin_amdgcn_sched_barrier(0);
    __builtin_amdgcn_s_barrier();
    __builtin_amdgcn_sched_barrier(0);

    #pragma unroll
    for (int kk = 0; kk < 2; ++kk) {
      bf16x8 av[FM], bv[FN];
      #pragma unroll
      for (int f = 0; f < FM; ++f) {
        const int ra = wm * (FM * 16) + (f << 4) + r16;
        av[f] = *(const bf16x8*)&Al[cur][0][(ra << 6) + ((((kk << 2) + ch) ^ (ra & 7)) << 3)];
      }
      #pragma unroll
      for (int f = 0; f < FN; ++f) {
        const int rb = wn * (FN * 16) + (f << 4) + r16;
        bv[f] = *(const bf16x8*)&Bl[cur][0][(rb << 6) + ((((kk << 2) + ch) ^ (rb & 7)) << 3)];
      }
      bf16x8 av1[FM], bv1[FN];
      if constexpr (NA == 2) {
        #pragma unroll
        for (int f = 0; f < FM; ++f) {
          const int ra = wm * (FM * 16) + (f << 4) + r16;
          av1[f] = *(const bf16x8*)&Al[cur][NA - 1][(ra << 6) + ((((kk << 2) + ch) ^ (ra & 7)) << 3)];
        }
      }
      if constexpr (NB2 == 2) {
        #pragma unroll
        for (int f = 0; f < FN; ++f) {
          const int rb = wn * (FN * 16) + (f << 4) + r16;
          bv1[f] = *(const bf16x8*)&Bl[cur][1][(rb << 6) + ((((kk << 2) + ch) ^ (rb & 7)) << 3)];
        }
      }
      __builtin_amdgcn_s_setprio(1);
      #pragma unroll
      for (int fm = 0; fm < FM; ++fm)
        #pragma unroll
        for (int fn = 0; fn < FN; ++fn)
          acc[fm][fn] = __builtin_amdgcn_mfma_f32_16x16x32_bf16(av[fm], bv[fn], acc[fm][fn], 0, 0, 0);
      if constexpr (NA == 2) {
        #pragma unroll
        for (int fm = 0; fm < FM; ++fm)
          #pragma unroll
          for (int fn = 0; fn < FN; ++fn)
            acc[fm][fn] = __builtin_amdgcn_mfma_f32_16x16x32_bf16(av1[fm], bv[fn], acc[fm][fn], 0, 0, 0);
      }
      if constexpr (NB2 == 2) {
        #pragma unroll
        for (int fm = 0; fm < FM; ++fm)
          #pragma unroll
          for (int fn = 0; fn < FN; ++fn)
            acc[fm][fn] = __builtin_amdgcn_mfma_f32_16x16x32_bf16(av[fm], bv1[fn], acc[fm][fn], 0, 0, 0);
      }
      __builtin_amdgcn_s_setprio(0);
    }
    __builtin_amdgcn_sched_barrier(0);
    __builtin_amdgcn_s_barrier();
    __builtin_amdgcn_sched_barrier(0);
  }

  // epilogue: C/D layout: col = lane&15, row = (lane>>4)*4 + j
  const int rbase = row0 + wm * (FM * 16) + ((lane >> 4) << 2);
  const int cbase = col0 + wn * (FN * 16) + (lane & 15);
  #pragma unroll
  for (int fm = 0; fm < FM; ++fm)
    #pragma unroll
    for (int fn = 0; fn < FN; ++fn)
      #pragma unroll
      for (int j = 0; j < 4; ++j) {
        const int gr = rbase + (fm << 4) + j;
        const int gc = cbase + (fn << 4);
        const float a = acc[fm][fn][j];
        if constexpr (EPI == 0) {
          float v = alpha * a;
          if (auxH) v += beta * h2f(auxH[(size_t)gr * ldc + gc]);
          if (gamma != 0.f && gr == gc) v += gamma;
          const u16 hh = f2h(v);
          outH[(size_t)gr * ldc + gc] = hh;
          if (outL) outL[(size_t)gr * ldc + gc] = f2h(v - h2f(hh));
        } else if constexpr (EPI == 1) {
          outH[(size_t)gr * ldc + gc] = f2h(a + h2f(auxH[(size_t)gr * ldc + gc]));
        } else {
          outF[(size_t)gr * ldc + gc] =
              (gr < NU) ? (auxF[(size_t)gr * ldc + gc] + 0.1f * qv[gr] - a) : a;
        }
      }
}

extern "C" void kernel_launch(void* const* d_in, const int* in_sizes, int n_in,
                              void* d_out, int out_size, void* d_ws, size_t ws_size,
                              hipStream_t stream) {
  (void)in_sizes; (void)n_in; (void)out_size; (void)ws_size;
  const float* v0 = (const float*)d_in[0];
  const float* v1 = (const float*)d_in[1];
  const float* B0 = (const float*)d_in[2];
  const float* q  = (const float*)d_in[3];
  float* out = (float*)d_out;

  size_t off = 0;
  char* base = (char*)d_ws;
  auto alloc = [&](size_t bytes) -> u16* {
    char* r = base + off;
    off += (bytes + 255) & ~(size_t)255;
    return (u16*)r;
  };
  u16* z1T  = alloc((size_t)NBB * NU * 2);  // 16.8 MB
  u16* z2T  = alloc((size_t)NBB * NU * 2);  // 16.8 MB
  u16* t1T  = alloc((size_t)NBB * NU * 2);  // 16.8 MB
  u16* B0h  = alloc((size_t)NU * NU * 2);
  u16* B0Th = alloc((size_t)NU * NU * 2);
  u16* B0Tl = alloc((size_t)NU * NU * 2);
  u16* Mh   = alloc((size_t)NU * NU * 2);
  u16* Ml   = alloc((size_t)NU * NU * 2);
  u16* S1   = alloc((size_t)NU * NU * 2);
  u16* S2   = alloc((size_t)NU * NU * 2);
  u16* S3   = alloc((size_t)NU * NU * 2);   // total ~67 MB

  const u16* NH = nullptr;
  const float* NF = nullptr;

  prep_b0<<<dim3(32, 32), dim3(32, 8), 0, stream>>>(B0, B0h, B0Th, B0Tl);
  build_zT<<<dim3(NBB / 32, NU / 32), dim3(32, 8), 0, stream>>>(v0, v1, q, z1T, z2T);

  // M = 2I + B0^T B0 in split precision (hh + lh + hl) -> Mh + Ml
  gemm_u<64, 64, 2, 2, 4, 0><<<256, 256, 0, stream>>>(
      B0Th, B0Tl, B0Th, B0Tl, NU, NU, NH, NF, NF,
      1.f, 0.f, 2.f, nullptr, Mh, Ml, NU, NU, NU, NU);
  // M2 = M*M
  gemm_u<64, 64, 2, 2, 2, 0><<<256, 256, 0, stream>>>(
      Mh, nullptr, Mh, nullptr, NU, NU, NH, NF, NF,
      1.f, 0.f, 0.f, nullptr, S1, nullptr, NU, NU, NU, NU);
  // G = C2 I + C3 M + C4 M2
  build_g<<<NU * NU / 256, 256, 0, stream>>>(Mh, S1, S2);
  // X0 = M2*G + C1*M + C0*I  (deg-4 Chebyshev)
  gemm_u<64, 64, 2, 2, 2, 0><<<256, 256, 0, stream>>>(
      S1, nullptr, S2, nullptr, NU, NU, Mh, NF, NF,
      1.f, C1, C0, nullptr, S3, nullptr, NU, NU, NU, NU);
  // E = I - M*X0 (split M, exact via X0^T)
  transpose_h<<<dim3(32, 32), dim3(32, 8), 0, stream>>>(S3, S2);           // X0^T
  gemm_u<64, 64, 2, 2, 3, 0><<<256, 256, 0, stream>>>(
      Mh, Ml, S2, nullptr, NU, NU, NH, NF, NF,
      -1.f, 0.f, 1.f, nullptr, S1, nullptr, NU, NU, NU, NU);
  // P = X0 + X0*E  (via E^T) -> Ml slot
  transpose_h<<<dim3(32, 32), dim3(32, 8), 0, stream>>>(S1, S2);           // E^T
  gemm_u<64, 64, 2, 2, 2, 0><<<256, 256, 0, stream>>>(
      S3, nullptr, S2, nullptr, NU, NU, S3, NF, NF,
      1.f, 1.f, 0.f, nullptr, Ml, nullptr, NU, NU, NU, NU);
  // R = B0 * P (P ~ symmetric) -> Mh slot
  gemm_u<64, 64, 2, 2, 2, 0><<<256, 256, 0, stream>>>(
      B0h, nullptr, Ml, nullptr, NU, NU, NH, NF, NF,
      1.f, 0.f, 0.f, nullptr, Mh, nullptr, NU, NU, NU, NU);

  // apply A: t1T = z1T * B0 + z2T   (8192 x 1024 x 1024)
  gemm_u<256, 128, 4, 2, 2, 1><<<256, 512, 0, stream>>>(
      z1T, nullptr, B0Th, nullptr, NU, NU, z2T, NF, NF,
      0.f, 0.f, 0.f, nullptr, t1T, nullptr, NU, NBB, NU, NU);
  // apply BC: [x; y] with A = [R; P] stacked (2048 x 8192 x 1024)
  gemm_u<128, 256, 2, 4, 2, 2><<<512, 512, 0, stream>>>(
      Mh, Ml, t1T, nullptr, NU, NU, NH, v0, q,
      0.f, 0.f, 0.f, out, nullptr, nullptr, NBB, 2 * NU, NBB, NU);
}